// Round 4
// baseline (3086.408 us; speedup 1.0000x reference)
//
#include <hip/hip_runtime.h>

#define N_NODES 100000
#define D 64

// ---------------------------------------------------------------------------
// Scatter: agg[dst] += x[src] over all edges. 16 threads per edge, each
// thread owns one float4 chunk (4 features). Gather is coalesced (16 threads
// cover the full 256B row); scatter uses HW f32 atomics (agent scope).
// ---------------------------------------------------------------------------
__global__ __launch_bounds__(256) void scatter_kernel(
    const float* __restrict__ x,
    const int* __restrict__ src,
    const int* __restrict__ dst,
    float* __restrict__ agg,
    long total_chunks)  // n_edges * 16
{
    long tid = (long)blockIdx.x * blockDim.x + threadIdx.x;
    if (tid >= total_chunks) return;
    int e = (int)(tid >> 4);
    int c = (int)(tid & 15);
    int s = src[e];
    int d = dst[e];
    const float4 v = *reinterpret_cast<const float4*>(&x[(long)s * D + c * 4]);
    float* p = &agg[(long)d * D + c * 4];
    __hip_atomic_fetch_add(p + 0, v.x, __ATOMIC_RELAXED, __HIP_MEMORY_SCOPE_AGENT);
    __hip_atomic_fetch_add(p + 1, v.y, __ATOMIC_RELAXED, __HIP_MEMORY_SCOPE_AGENT);
    __hip_atomic_fetch_add(p + 2, v.z, __ATOMIC_RELAXED, __HIP_MEMORY_SCOPE_AGENT);
    __hip_atomic_fetch_add(p + 3, v.w, __ATOMIC_RELAXED, __HIP_MEMORY_SCOPE_AGENT);
}

// ---------------------------------------------------------------------------
// Dense epilogue: out = [relu](agg @ Wrel^T + b + xin @ Wroot^T)
// One wave per node. W matrices staged TRANSPOSED in LDS so the inner read
// WrelT[k*64 + lane] is lane-consecutive (conflict-free). Row values are
// broadcast with __shfl at compile-time lane index (v_readlane -> SGPR).
// Safe to run in-place (out == xin): each wave reads its entire row into
// registers before writing it, and rows are disjoint across waves.
// ---------------------------------------------------------------------------
template <int RELU>
__global__ __launch_bounds__(256) void dense_kernel(
    const float* __restrict__ agg,
    const float* __restrict__ xin,
    const float* __restrict__ Wrel,
    const float* __restrict__ brel,
    const float* __restrict__ Wroot,
    float* __restrict__ out)
{
    __shared__ float WrelT[D * D];
    __shared__ float WrootT[D * D];
    const int tid = threadIdx.x;
    for (int i = tid; i < D * D; i += 256) {
        int j = i >> 6;      // row of W
        int k = i & 63;      // col of W
        WrelT[k * D + j] = Wrel[i];
        WrootT[k * D + j] = Wroot[i];
    }
    __syncthreads();

    const int lane = tid & 63;
    const int wave = tid >> 6;
    const float bias = brel[lane];
    const int stride = gridDim.x * 4;

    for (int node = blockIdx.x * 4 + wave; node < N_NODES; node += stride) {
        const float a  = agg[(long)node * D + lane];
        const float xv = xin[(long)node * D + lane];
        float acc = bias;
#pragma unroll
        for (int k = 0; k < D; ++k) {
            const float ak = __shfl(a, k);
            const float xk = __shfl(xv, k);
            acc += ak * WrelT[k * D + lane];
            acc += xk * WrootT[k * D + lane];
        }
        if (RELU) acc = fmaxf(acc, 0.0f);
        out[(long)node * D + lane] = acc;
    }
}

extern "C" void kernel_launch(void* const* d_in, const int* in_sizes, int n_in,
                              void* d_out, int out_size, void* d_ws, size_t ws_size,
                              hipStream_t stream)
{
    const float* x     = (const float*)d_in[0];
    const int*   ei    = (const int*)d_in[1];
    const float* Wrel1 = (const float*)d_in[2];
    const float* brel1 = (const float*)d_in[3];
    const float* Wroot1= (const float*)d_in[4];
    const float* Wrel2 = (const float*)d_in[5];
    const float* brel2 = (const float*)d_in[6];
    const float* Wroot2= (const float*)d_in[7];
    float* out = (float*)d_out;

    const int n_edges = in_sizes[1] / 2;
    const int* src = ei;
    const int* dst = ei + n_edges;

    float* agg = (float*)d_ws;  // 100000*64 f32 = 25.6 MB
    const size_t aggBytes = (size_t)N_NODES * D * sizeof(float);

    const long total_chunks = (long)n_edges * 16;
    const int sblocks = (int)((total_chunks + 255) / 256);
    const int dblocks = 1024;

    // ---- layer 1 ----
    hipMemsetAsync(agg, 0, aggBytes, stream);
    scatter_kernel<<<sblocks, 256, 0, stream>>>(x, src, dst, agg, total_chunks);
    // h = relu(agg@Wrel1^T + b1 + x@Wroot1^T), stored in d_out
    dense_kernel<1><<<dblocks, 256, 0, stream>>>(agg, x, Wrel1, brel1, Wroot1, out);

    // ---- layer 2 ----
    hipMemsetAsync(agg, 0, aggBytes, stream);
    scatter_kernel<<<sblocks, 256, 0, stream>>>(out, src, dst, agg, total_chunks);
    // out = agg@Wrel2^T + b2 + h@Wroot2^T (in place on d_out)
    dense_kernel<0><<<dblocks, 256, 0, stream>>>(agg, out, Wrel2, brel2, Wroot2, out);
}

// Round 9
// 735.948 us; speedup vs baseline: 4.1938x; 4.1938x over previous
//
#include <hip/hip_runtime.h>
#include <hip/hip_bf16.h>

#define N_NODES 100000
#define D 64
#define SCAN_N (N_NODES + 1)   // row_start has N+1 entries
#define CHUNK 1024
#define NBLK ((SCAN_N + CHUNK - 1) / CHUNK)   // 98

// ---------------- CSR build: histogram -> 2-level exclusive scan -> fill ----

__global__ __launch_bounds__(256) void hist_kernel(
    const int* __restrict__ dst, int* __restrict__ deg, int n_edges)
{
    int i = blockIdx.x * blockDim.x + threadIdx.x;
    if (i < n_edges) atomicAdd(&deg[dst[i]], 1);
}

__global__ __launch_bounds__(CHUNK) void scan_part1(
    const int* __restrict__ deg, int* __restrict__ bsum)
{
    __shared__ int tmp[CHUNK];
    int i = blockIdx.x * CHUNK + threadIdx.x;
    tmp[threadIdx.x] = (i < SCAN_N) ? deg[i] : 0;
    __syncthreads();
    for (int off = CHUNK / 2; off > 0; off >>= 1) {
        if (threadIdx.x < off) tmp[threadIdx.x] += tmp[threadIdx.x + off];
        __syncthreads();
    }
    if (threadIdx.x == 0) bsum[blockIdx.x] = tmp[0];
}

__global__ __launch_bounds__(128) void scan_part2(int* __restrict__ bsum)
{
    __shared__ int tmp[128];
    int v = (threadIdx.x < NBLK) ? bsum[threadIdx.x] : 0;
    tmp[threadIdx.x] = v;
    __syncthreads();
    for (int off = 1; off < 128; off <<= 1) {
        int t = (threadIdx.x >= off) ? tmp[threadIdx.x - off] : 0;
        __syncthreads();
        tmp[threadIdx.x] += t;
        __syncthreads();
    }
    if (threadIdx.x < NBLK) bsum[threadIdx.x] = tmp[threadIdx.x] - v;  // exclusive
}

__global__ __launch_bounds__(CHUNK) void scan_part3(
    const int* __restrict__ deg, const int* __restrict__ bsum,
    int* __restrict__ row_start, int* __restrict__ cursor)
{
    __shared__ int tmp[CHUNK];
    int i = blockIdx.x * CHUNK + threadIdx.x;
    int v = (i < SCAN_N) ? deg[i] : 0;
    tmp[threadIdx.x] = v;
    __syncthreads();
    for (int off = 1; off < CHUNK; off <<= 1) {
        int t = (threadIdx.x >= off) ? tmp[threadIdx.x - off] : 0;
        __syncthreads();
        tmp[threadIdx.x] += t;
        __syncthreads();
    }
    if (i < SCAN_N) {
        int excl = bsum[blockIdx.x] + tmp[threadIdx.x] - v;
        row_start[i] = excl;
        if (i < N_NODES) cursor[i] = excl;
    }
}

__global__ __launch_bounds__(256) void fill_kernel(
    const int* __restrict__ src, const int* __restrict__ dst,
    int* __restrict__ cursor, int* __restrict__ esrc, int n_edges)
{
    int i = blockIdx.x * blockDim.x + threadIdx.x;
    if (i < n_edges) {
        int pos = atomicAdd(&cursor[dst[i]], 1);
        esrc[pos] = src[i];
    }
}

// ---------------- fused layer: gather (CSR) + dual-GEMM epilogue ------------

__device__ __forceinline__ float ldv(const float* p) { return *p; }
__device__ __forceinline__ float ldv(const __hip_bfloat16* p) { return __bfloat162float(*p); }
__device__ __forceinline__ void stv(float* p, float v) { *p = v; }
__device__ __forceinline__ void stv(__hip_bfloat16* p, float v) { *p = __float2bfloat16(v); }

// out_i = [relu]( Wrel @ (sum_{j->i} in_j) + b + Wroot @ in_i )
// One wave per node; lane = feature. agg lives in registers, never in memory.
template <typename IT, typename OT, int RELU>
__global__ __launch_bounds__(256) void layer_kernel(
    const IT* __restrict__ xin,
    const int* __restrict__ row_start,
    const int* __restrict__ esrc,
    const float* __restrict__ Wrel,
    const float* __restrict__ brel,
    const float* __restrict__ Wroot,
    OT* __restrict__ out)
{
    __shared__ float WrelT[D * D];
    __shared__ float WrootT[D * D];
    const int tid = threadIdx.x;
    for (int i = tid; i < D * D; i += 256) {
        int j = i >> 6, k = i & 63;
        WrelT[k * D + j] = Wrel[i];
        WrootT[k * D + j] = Wroot[i];
    }
    __syncthreads();

    const int lane = tid & 63;
    const int wave = tid >> 6;
    const float bias = brel[lane];
    const int stride = gridDim.x * 4;

    for (int node = blockIdx.x * 4 + wave; node < N_NODES; node += stride) {
        const int beg = row_start[node];
        const int end = row_start[node + 1];
        float agg = 0.0f;
        int e = beg;
        for (; e + 4 <= end; e += 4) {
            int s0 = esrc[e], s1 = esrc[e + 1], s2 = esrc[e + 2], s3 = esrc[e + 3];
            float v0 = ldv(&xin[(long)s0 * D + lane]);
            float v1 = ldv(&xin[(long)s1 * D + lane]);
            float v2 = ldv(&xin[(long)s2 * D + lane]);
            float v3 = ldv(&xin[(long)s3 * D + lane]);
            agg += (v0 + v1) + (v2 + v3);
        }
        for (; e < end; ++e) agg += ldv(&xin[(long)esrc[e] * D + lane]);

        const float xv = ldv(&xin[(long)node * D + lane]);
        float acc = bias;
#pragma unroll
        for (int k = 0; k < D; ++k) {
            acc += __shfl(agg, k) * WrelT[k * D + lane];
            acc += __shfl(xv, k) * WrootT[k * D + lane];
        }
        if (RELU) acc = fmaxf(acc, 0.0f);
        stv(&out[(long)node * D + lane], acc);
    }
}

// ---------------------------------------------------------------------------

extern "C" void kernel_launch(void* const* d_in, const int* in_sizes, int n_in,
                              void* d_out, int out_size, void* d_ws, size_t ws_size,
                              hipStream_t stream)
{
    const float* x     = (const float*)d_in[0];
    const int*   ei    = (const int*)d_in[1];
    const float* Wrel1 = (const float*)d_in[2];
    const float* brel1 = (const float*)d_in[3];
    const float* Wroot1= (const float*)d_in[4];
    const float* Wrel2 = (const float*)d_in[5];
    const float* brel2 = (const float*)d_in[6];
    const float* Wroot2= (const float*)d_in[7];
    float* out = (float*)d_out;

    const int n_edges = in_sizes[1] / 2;
    const int* src = ei;
    const int* dst = ei + n_edges;

    // workspace layout (ints)
    int* base      = (int*)d_ws;
    int* row_start = base;                       // SCAN_N
    int* deg       = base + 100352;              // SCAN_N
    int* cursor    = base + 200704;              // N_NODES
    int* bsum      = base + 301056;              // 128
    int* esrc      = base + 301184;              // n_edges
    const size_t h_off_bytes = (size_t)(301184 + n_edges) * 4;
    const size_t f32h_need = h_off_bytes + (size_t)N_NODES * D * 4 + 1024;

    // ---- build CSR (dst-sorted) ----
    hipMemsetAsync(deg, 0, (size_t)SCAN_N * sizeof(int), stream);
    hist_kernel<<<(n_edges + 255) / 256, 256, 0, stream>>>(dst, deg, n_edges);
    scan_part1<<<NBLK, CHUNK, 0, stream>>>(deg, bsum);
    scan_part2<<<1, 128, 0, stream>>>(bsum);
    scan_part3<<<NBLK, CHUNK, 0, stream>>>(deg, bsum, row_start, cursor);
    fill_kernel<<<(n_edges + 255) / 256, 256, 0, stream>>>(src, dst, cursor, esrc, n_edges);

    const int LB = 2048;  // layer-kernel blocks (grid-stride, 4 waves each)

    if (ws_size >= f32h_need) {
        float* h = (float*)((char*)d_ws + h_off_bytes);
        layer_kernel<float, float, 1><<<LB, 256, 0, stream>>>(
            x, row_start, esrc, Wrel1, brel1, Wroot1, h);
        layer_kernel<float, float, 0><<<LB, 256, 0, stream>>>(
            h, row_start, esrc, Wrel2, brel2, Wroot2, out);
    } else {
        __hip_bfloat16* h = (__hip_bfloat16*)((char*)d_ws + h_off_bytes);
        layer_kernel<float, __hip_bfloat16, 1><<<LB, 256, 0, stream>>>(
            x, row_start, esrc, Wrel1, brel1, Wroot1, h);
        layer_kernel<__hip_bfloat16, float, 0><<<LB, 256, 0, stream>>>(
            h, row_start, esrc, Wrel2, brel2, Wroot2, out);
    }
}

// Round 10
// 648.287 us; speedup vs baseline: 4.7609x; 1.1352x over previous
//
#include <hip/hip_runtime.h>
#include <hip/hip_bf16.h>

#define N_NODES 100000
#define D 64
#define SCAN_N (N_NODES + 1)
#define CHUNK 1024
#define NBLK ((SCAN_N + CHUNK - 1) / CHUNK)   // 98

// ---------------- CSR build: histogram -> 2-level exclusive scan -> fill ----

__global__ __launch_bounds__(256) void hist_kernel(
    const int* __restrict__ dst, int* __restrict__ deg, int n_edges)
{
    int i = blockIdx.x * blockDim.x + threadIdx.x;
    if (i < n_edges) atomicAdd(&deg[dst[i]], 1);
}

__global__ __launch_bounds__(CHUNK) void scan_part1(
    const int* __restrict__ deg, int* __restrict__ bsum)
{
    __shared__ int tmp[CHUNK];
    int i = blockIdx.x * CHUNK + threadIdx.x;
    tmp[threadIdx.x] = (i < SCAN_N) ? deg[i] : 0;
    __syncthreads();
    for (int off = CHUNK / 2; off > 0; off >>= 1) {
        if (threadIdx.x < off) tmp[threadIdx.x] += tmp[threadIdx.x + off];
        __syncthreads();
    }
    if (threadIdx.x == 0) bsum[blockIdx.x] = tmp[0];
}

__global__ __launch_bounds__(128) void scan_part2(int* __restrict__ bsum)
{
    __shared__ int tmp[128];
    int v = (threadIdx.x < NBLK) ? bsum[threadIdx.x] : 0;
    tmp[threadIdx.x] = v;
    __syncthreads();
    for (int off = 1; off < 128; off <<= 1) {
        int t = (threadIdx.x >= off) ? tmp[threadIdx.x - off] : 0;
        __syncthreads();
        tmp[threadIdx.x] += t;
        __syncthreads();
    }
    if (threadIdx.x < NBLK) bsum[threadIdx.x] = tmp[threadIdx.x] - v;  // exclusive
}

__global__ __launch_bounds__(CHUNK) void scan_part3(
    const int* __restrict__ deg, const int* __restrict__ bsum,
    int* __restrict__ row_start, int* __restrict__ cursor)
{
    __shared__ int tmp[CHUNK];
    int i = blockIdx.x * CHUNK + threadIdx.x;
    int v = (i < SCAN_N) ? deg[i] : 0;
    tmp[threadIdx.x] = v;
    __syncthreads();
    for (int off = 1; off < CHUNK; off <<= 1) {
        int t = (threadIdx.x >= off) ? tmp[threadIdx.x - off] : 0;
        __syncthreads();
        tmp[threadIdx.x] += t;
        __syncthreads();
    }
    if (i < SCAN_N) {
        int excl = bsum[blockIdx.x] + tmp[threadIdx.x] - v;
        row_start[i] = excl;
        if (i < N_NODES) cursor[i] = excl;
    }
}

__global__ __launch_bounds__(256) void fill_kernel(
    const int* __restrict__ src, const int* __restrict__ dst,
    int* __restrict__ cursor, int* __restrict__ esrc, int n_edges)
{
    int i = blockIdx.x * blockDim.x + threadIdx.x;
    if (i < n_edges) {
        int pos = atomicAdd(&cursor[dst[i]], 1);
        esrc[pos] = src[i];
    }
}

// ---------------- type helpers ----------------------------------------------

__device__ __forceinline__ float ldv(const float* p) { return *p; }
__device__ __forceinline__ float ldv(const __hip_bfloat16* p) { return __bfloat162float(*p); }

__device__ __forceinline__ void st4(float* p, float4 v) { *reinterpret_cast<float4*>(p) = v; }
__device__ __forceinline__ void st4(__hip_bfloat16* p, float4 v) {
    p[0] = __float2bfloat16(v.x); p[1] = __float2bfloat16(v.y);
    p[2] = __float2bfloat16(v.z); p[3] = __float2bfloat16(v.w);
}

// ---------------- gather: agg[i] = sum_{j->i} xin[j] ------------------------
// One wave per node. lane = g*16+c: edge-slot g (4 edges in parallel),
// float4 chunk c. No LDS, low VGPR -> max occupancy; 8 edges (2 KB) in
// flight per wave. Full row written -> no memset of agg needed.
template <typename AT>
__global__ __launch_bounds__(256) void gather_kernel(
    const float* __restrict__ xin,
    const int* __restrict__ row_start,
    const int* __restrict__ esrc,
    AT* __restrict__ agg)
{
    const int wid = (blockIdx.x * 256 + threadIdx.x) >> 6;   // node
    if (wid >= N_NODES) return;
    const int lane = threadIdx.x & 63;
    const int g = lane >> 4;      // 0..3 edge slot
    const int c = lane & 15;      // 0..15 float4 chunk

    const int beg = row_start[wid];
    const int end = row_start[wid + 1];

    float4 acc = make_float4(0.f, 0.f, 0.f, 0.f);
    for (int e = beg; e < end; e += 8) {
        const int i0 = e + g;
        const int i1 = e + 4 + g;
        if (i0 < end) {
            const float4 v = *reinterpret_cast<const float4*>(
                &xin[(long)esrc[i0] * D + c * 4]);
            acc.x += v.x; acc.y += v.y; acc.z += v.z; acc.w += v.w;
        }
        if (i1 < end) {
            const float4 v = *reinterpret_cast<const float4*>(
                &xin[(long)esrc[i1] * D + c * 4]);
            acc.x += v.x; acc.y += v.y; acc.z += v.z; acc.w += v.w;
        }
    }
    // reduce the 4 edge slots (lane bits 4,5)
    acc.x += __shfl_xor(acc.x, 16); acc.y += __shfl_xor(acc.y, 16);
    acc.z += __shfl_xor(acc.z, 16); acc.w += __shfl_xor(acc.w, 16);
    acc.x += __shfl_xor(acc.x, 32); acc.y += __shfl_xor(acc.y, 32);
    acc.z += __shfl_xor(acc.z, 32); acc.w += __shfl_xor(acc.w, 32);

    if (g == 0) st4(&agg[(long)wid * D + c * 4], acc);
}

// ---------------- dense: out = [relu](agg@Wrel^T + b + xin@Wroot^T) ---------
// Wave per node (grid-stride). LDS stride 65 kills the stride-64 staging
// bank conflict. In-place safe (out==xin): full row read before write.
#define LDS_S 65
template <typename AT, int RELU>
__global__ __launch_bounds__(256) void dense_kernel(
    const AT* __restrict__ agg,
    const float* __restrict__ xin,
    const float* __restrict__ Wrel,
    const float* __restrict__ brel,
    const float* __restrict__ Wroot,
    float* __restrict__ out)
{
    __shared__ float WrelT[D * LDS_S];
    __shared__ float WrootT[D * LDS_S];
    const int tid = threadIdx.x;
    for (int i = tid; i < D * D; i += 256) {
        int j = i >> 6, k = i & 63;
        WrelT[k * LDS_S + j] = Wrel[i];     // banks (k*65+j)%32 = (k+j)%32: conflict-free
        WrootT[k * LDS_S + j] = Wroot[i];
    }
    __syncthreads();

    const int lane = tid & 63;
    const int wave = tid >> 6;
    const float bias = brel[lane];
    const int stride = gridDim.x * 4;

    for (int node = blockIdx.x * 4 + wave; node < N_NODES; node += stride) {
        const float a  = ldv(&agg[(long)node * D + lane]);
        const float xv = xin[(long)node * D + lane];
        float acc = bias;
#pragma unroll
        for (int k = 0; k < D; ++k) {
            acc += __shfl(a, k) * WrelT[k * LDS_S + lane];
            acc += __shfl(xv, k) * WrootT[k * LDS_S + lane];
        }
        if (RELU) acc = fmaxf(acc, 0.0f);
        out[(long)node * D + lane] = acc;
    }
}

// ---------------------------------------------------------------------------

extern "C" void kernel_launch(void* const* d_in, const int* in_sizes, int n_in,
                              void* d_out, int out_size, void* d_ws, size_t ws_size,
                              hipStream_t stream)
{
    const float* x     = (const float*)d_in[0];
    const int*   ei    = (const int*)d_in[1];
    const float* Wrel1 = (const float*)d_in[2];
    const float* brel1 = (const float*)d_in[3];
    const float* Wroot1= (const float*)d_in[4];
    const float* Wrel2 = (const float*)d_in[5];
    const float* brel2 = (const float*)d_in[6];
    const float* Wroot2= (const float*)d_in[7];
    float* out = (float*)d_out;

    const int n_edges = in_sizes[1] / 2;
    const int* src = ei;
    const int* dst = ei + n_edges;

    // workspace layout (ints)
    int* base      = (int*)d_ws;
    int* row_start = base;                       // SCAN_N
    int* deg       = base + 100352;              // SCAN_N
    int* cursor    = base + 200704;              // N_NODES
    int* bsum      = base + 301056;              // 128
    int* esrc      = base + 301184;              // n_edges
    const size_t agg_off = (((size_t)(301184 + n_edges) * 4) + 255) & ~(size_t)255;
    const size_t f32agg_need = agg_off + (size_t)N_NODES * D * 4 + 1024;

    // ---- build CSR (dst-sorted) ----
    hipMemsetAsync(deg, 0, (size_t)SCAN_N * sizeof(int), stream);
    hist_kernel<<<(n_edges + 255) / 256, 256, 0, stream>>>(dst, deg, n_edges);
    scan_part1<<<NBLK, CHUNK, 0, stream>>>(deg, bsum);
    scan_part2<<<1, 128, 0, stream>>>(bsum);
    scan_part3<<<NBLK, CHUNK, 0, stream>>>(deg, bsum, row_start, cursor);
    fill_kernel<<<(n_edges + 255) / 256, 256, 0, stream>>>(src, dst, cursor, esrc, n_edges);

    const int GB = (N_NODES * 64 + 255) / 256;   // gather: wave per node
    const int DB = 1024;                          // dense: grid-stride

    if (ws_size >= f32agg_need) {
        float* agg = (float*)((char*)d_ws + agg_off);
        // layer 1: h = relu(...) -> d_out
        gather_kernel<float><<<GB, 256, 0, stream>>>(x, row_start, esrc, agg);
        dense_kernel<float, 1><<<DB, 256, 0, stream>>>(agg, x, Wrel1, brel1, Wroot1, out);
        // layer 2: in place on d_out
        gather_kernel<float><<<GB, 256, 0, stream>>>(out, row_start, esrc, agg);
        dense_kernel<float, 0><<<DB, 256, 0, stream>>>(agg, out, Wrel2, brel2, Wroot2, out);
    } else {
        __hip_bfloat16* agg = (__hip_bfloat16*)((char*)d_ws + agg_off);
        gather_kernel<__hip_bfloat16><<<GB, 256, 0, stream>>>(x, row_start, esrc, agg);
        dense_kernel<__hip_bfloat16, 1><<<DB, 256, 0, stream>>>(agg, x, Wrel1, brel1, Wroot1, out);
        gather_kernel<__hip_bfloat16><<<GB, 256, 0, stream>>>(out, row_start, esrc, agg);
        dense_kernel<__hip_bfloat16, 0><<<DB, 256, 0, stream>>>(agg, out, Wrel2, brel2, Wroot2, out);
    }
}